// Round 2
// baseline (425.131 us; speedup 1.0000x reference)
//
#include <hip/hip_runtime.h>
#include <math.h>

#define IMG_H 1024
#define IMG_W 1024
#define OUT_H 1025
#define OUT_W 1025
#define NIMG  16
#define TOTAL (NIMG * OUT_H * OUT_W)

#define TILE_W 64
#define TILE_H 16
#define HALO_W 68                 // ox in [tile_ox-2, tile_ox+65]
#define HALO_H 18                 // oy in [tile_oy-1, tile_oy+16]
#define NQX    17                 // 68/4 x-quads per halo row
#define NQUAD  (HALO_H * NQX)     // 306
#define NTHREADS 320
#define YTILES 5                  // y-tiles per block (pipelined)
#define GRID_Y 13                 // 65 / YTILES

// Map bp (double-reflect-padded) row/col index k in [0,1026] to source image index.
__device__ __forceinline__ int refl(int k) {
    if (k >= 2) return (k <= 1025) ? (k - 2) : 1022;
    return k;
}

// Generic sobel at output (i,j) — exact f32 op order (bit-matched np in r1-r3).
__device__ __forceinline__ void sobel_generic(const float* __restrict__ img, int i, int j,
                                              float& gx, float& gy) {
    int r0 = refl(i), r1 = refl(i + 1), r2 = refl(i + 2);
    int c0 = refl(j), c1 = refl(j + 1), c2 = refl(j + 2);
    const float* p0 = img + r0 * IMG_W;
    const float* p1 = img + r1 * IMG_W;
    const float* p2 = img + r2 * IMG_W;
    float v00 = p0[c0], v01 = p0[c1], v02 = p0[c2];
    float v10 = p1[c0],               v12 = p1[c2];
    float v20 = p2[c0], v21 = p2[c1], v22 = p2[c2];

    float t = -v00;
    t = __fadd_rn(t, v02);
    t = __fadd_rn(t, -2.0f * v10);
    t = __fadd_rn(t, 2.0f * v12);
    t = __fadd_rn(t, -v20);
    gx = __fadd_rn(t, v22);

    t = -v00;
    t = __fadd_rn(t, -2.0f * v01);
    t = __fadd_rn(t, -v02);
    t = __fadd_rn(t, v20);
    t = __fadd_rn(t, 2.0f * v21);
    gy = __fadd_rn(t, v22);
}

// Exact reference binning (double atan2 -> f32 chain). Bit-matched np in r1.
// COLD path: only hit inside a ~1e-4-wide guard band around the bin edges.
__device__ int classify_slow(float gx, float gy) {
    float t = (float)atan2((double)gx, (double)gy);
    float deg = __fmul_rn(t, (float)(180.0 / M_PI));
    float th = __fadd_rn(deg, 90.0f);
    th = fmodf(th, 180.0f);
    if (th < 0.0f) th += 180.0f;
    if (th < 22.5f || th >= 157.5f) return 0;
    if (th < 67.5f) return 1;
    if (th < 112.5f) return 2;
    return 3;
}

// Fast binning: sign + ratio comparisons with guard band (bit-matched np in r2/r3).
__device__ __forceinline__ int classify(float gx, float gy) {
    float ax = fabsf(gx), ay = fabsf(gy);
    const float T22_LO = 0.414172141e0f;
    const float T22_HI = 0.414254984e0f;
    const float T67_LO = 2.413972141e0f;
    const float T67_HI = 2.414454984e0f;

    if (ax <= ay * T22_LO) return 2;                  // (0,0) lands here: bin 2
    if (ax >= ay * T67_HI) return 0;
    if (ax >= ay * T22_HI && ax <= ay * T67_LO) {
        unsigned s = (__float_as_uint(gx) ^ __float_as_uint(gy)) >> 31;
        return s ? 1 : 3;
    }
    return classify_slow(gx, gy);
}

__device__ __forceinline__ float mag(float gx, float gy) {
    return __fsqrt_rn(__fadd_rn(__fmul_rn(gx, gx), __fmul_rn(gy, gy)));
}

__device__ __forceinline__ void load6(const float* __restrict__ p, float v[6]) {
    float4 a = *(const float4*)p;        // 16B aligned: col base ≡ 0 (mod 4)
    float2 b = *(const float2*)(p + 4);
    v[0] = a.x; v[1] = a.y; v[2] = a.z; v[3] = a.w; v[4] = b.x; v[5] = b.y;
}

// Pipelined block: YTILES y-adjacent tiles per block. Per tile:
//   issue prefetch(t+1) -> nxt regs; sobel(t) from cur regs; LDS write g/b[buf];
//   ONE barrier; NMS+stores from LDS[buf]; cur=nxt; buf^=1.
// Double-buffered g/b LDS makes one barrier per tile legal: writes to buf^1
// can't collide with in-flight reads of buf; buf is rewritten only after the
// NEXT barrier. Prefetch regs are consumed a full tile later (>1000 cyc) so
// the compiler-inserted s_waitcnt vmcnt on first use never stalls.
__global__ __launch_bounds__(NTHREADS) void canny_kernel(const float* __restrict__ images,
                                                         float* __restrict__ out) {
    __shared__ float    g_s[2][HALO_H * HALO_W];
    __shared__ unsigned b_u[2][HALO_H * NQX];

    const int tile_ox = blockIdx.x * TILE_W;
    const int ty0     = blockIdx.y * YTILES;
    const int n       = blockIdx.z;
    const float* img = images + (size_t)n * IMG_H * IMG_W;
    const int t = threadIdx.x;

    const bool worker = (t < NQUAD);
    int hy = 0, qx = 0, ox0 = 0;
    if (worker) {
        hy  = t / NQX;
        qx  = t - hy * NQX;
        ox0 = tile_ox + qx * 4 - 2;   // ≡ 2 (mod 4)
    }
    const bool xin = (ox0 >= 2 && ox0 <= 1020);

    float cur[3][6], nxt[3][6];

    // Prologue: prefetch tile 0 (interior threads only; boundary threads load
    // at compute time via sobel_generic).
    if (worker) {
        int oy = ty0 * TILE_H + hy - 1;
        if (oy >= 2 && oy <= 1023 && xin) {
            const float* r0p = img + (oy - 2) * IMG_W + (ox0 - 2);
            load6(r0p,             cur[0]);
            load6(r0p + IMG_W,     cur[1]);
            load6(r0p + 2 * IMG_W, cur[2]);
        }
    }

    #pragma unroll 1
    for (int s = 0; s < YTILES; s++) {
        const int tile_oy = (ty0 + s) * TILE_H;
        const int buf = s & 1;

        // ---- issue prefetch for tile s+1 (latency hidden under this whole tile) ----
        if (worker && s + 1 < YTILES) {
            int oyn = tile_oy + TILE_H + hy - 1;
            if (oyn >= 2 && oyn <= 1023 && xin) {
                const float* r0p = img + (oyn - 2) * IMG_W + (ox0 - 2);
                load6(r0p,             nxt[0]);
                load6(r0p + IMG_W,     nxt[1]);
                load6(r0p + 2 * IMG_W, nxt[2]);
            }
        }

        // ---- Phase 1: g + bin for the 18x68 halo, one x-quad per thread ----
        if (worker) {
            int oy = tile_oy + hy - 1;
            float    gxs[4], gys[4], gq[4];
            unsigned bq[4];

            if (oy >= 2 && oy <= 1023 && xin) {
                // Interior: sobel from the prefetched rows (exact f32 op order).
                #pragma unroll
                for (int p = 0; p < 4; p++) {
                    float v00 = cur[0][p], v01 = cur[0][p + 1], v02 = cur[0][p + 2];
                    float v10 = cur[1][p],                      v12 = cur[1][p + 2];
                    float v20 = cur[2][p], v21 = cur[2][p + 1], v22 = cur[2][p + 2];

                    float sx = -v00;
                    sx = __fadd_rn(sx, v02);
                    sx = __fadd_rn(sx, -2.0f * v10);
                    sx = __fadd_rn(sx, 2.0f * v12);
                    sx = __fadd_rn(sx, -v20);
                    float gx = __fadd_rn(sx, v22);

                    sx = -v00;
                    sx = __fadd_rn(sx, -2.0f * v01);
                    sx = __fadd_rn(sx, -v02);
                    sx = __fadd_rn(sx, v20);
                    sx = __fadd_rn(sx, 2.0f * v21);
                    float gy = __fadd_rn(sx, v22);

                    gxs[p] = gx;
                    gys[p] = gy;
                    gq[p]  = mag(gx, gy);
                }
            } else {
                // Boundary quad: per-pixel generic (reflection + bounds), direct loads.
                #pragma unroll
                for (int p = 0; p < 4; p++) {
                    int ox = ox0 + p;
                    if (oy >= 0 && oy < OUT_H && ox >= 0 && ox < OUT_W) {
                        float gx, gy;
                        sobel_generic(img, oy, ox, gx, gy);
                        gxs[p] = gx;
                        gys[p] = gy;
                        gq[p]  = mag(gx, gy);
                    } else {
                        gxs[p] = 0.0f;
                        gys[p] = 1.0f;
                        gq[p]  = -1.0f;      // sentinel: invalid halo px
                    }
                }
            }

            // Classify after input rows are dead (cold f64-atan2 guard band).
            #pragma unroll
            for (int p = 0; p < 4; p++) {
                bq[p] = (gq[p] < 0.0f) ? 255u : (unsigned)classify(gxs[p], gys[p]);
            }

            int ldoff = hy * HALO_W + qx * 4;            // dword index, multiple of 4
            *(float4*)&g_s[buf][ldoff] = make_float4(gq[0], gq[1], gq[2], gq[3]);
            b_u[buf][hy * NQX + qx] = bq[0] | (bq[1] << 8) | (bq[2] << 16) | (bq[3] << 24);
        }
        __syncthreads();

        // ---- Phase 2: NMS + thresholds from LDS[buf] ----
        const float*         gs  = g_s[buf];
        const unsigned char* b_s = (const unsigned char*)b_u[buf];
        #pragma unroll
        for (int q = 0; q < 4; q++) {
            int p = t + NTHREADS * q;
            if (p >= TILE_W * TILE_H) break;             // only q=3 is partial
            int r = p >> 6, c = p & 63;
            int oy = tile_oy + r, ox = tile_ox + c;
            if (oy >= OUT_H || ox >= OUT_W) continue;

            int hc = (r + 1) * HALO_W + (c + 2);
            float gc = gs[hc];
            int   bc = b_s[hc];

            int doff = (bc == 0) ? 1
                     : (bc == 1) ? (HALO_W - 1)
                     : (bc == 2) ? HALO_W
                     :             (HALO_W + 1);

            float nmax = 0.0f;
            float g1 = gs[hc + doff];
            if (b_s[hc + doff] == bc && g1 > nmax) nmax = g1;
            float g2 = gs[hc - doff];
            if (b_s[hc - doff] == bc && g2 > nmax) nmax = g2;

            float e = (gc >= nmax) ? gc : 0.0f;

            size_t o = (size_t)(n * OUT_H + oy) * OUT_W + ox;
            out[o]                       = (e >= 50.0f) ? 255.5f : 0.0f;
            out[(size_t)TOTAL + o]       = (e >= 50.0f && e < 100.0f) ? 255.0f : 0.0f;
            out[(size_t)(2 * TOTAL) + o] = (e >= 100.0f) ? 255.0f : 0.0f;
        }

        // ---- rotate prefetch regs (static indices -> stays in VGPRs) ----
        if (worker && s + 1 < YTILES) {
            #pragma unroll
            for (int r = 0; r < 3; r++)
                #pragma unroll
                for (int c = 0; c < 6; c++)
                    cur[r][c] = nxt[r][c];
        }
    }
}

extern "C" void kernel_launch(void* const* d_in, const int* in_sizes, int n_in,
                              void* d_out, int out_size, void* d_ws, size_t ws_size,
                              hipStream_t stream) {
    const float* images = (const float*)d_in[0];
    float* out = (float*)d_out;
    dim3 grid((OUT_W + TILE_W - 1) / TILE_W,   // 17
              GRID_Y,                           // 13 (x5 tiles in-kernel = 65)
              NIMG);                            // 16
    canny_kernel<<<grid, NTHREADS, 0, stream>>>(images, out);
}

// Round 3
// 345.045 us; speedup vs baseline: 1.2321x; 1.2321x over previous
//
#include <hip/hip_runtime.h>
#include <math.h>

#define IMG_H 1024
#define IMG_W 1024
#define OUT_H 1025
#define OUT_W 1025
#define NIMG  16
#define TOTAL (NIMG * OUT_H * OUT_W)

// Wave-autonomous rolling-row decomposition: no __syncthreads anywhere.
#define STRIPW   62                 // output cols per wave (lanes 1..62)
#define NSTRIPS  17                 // 17*62 = 1054 >= 1025
#define NBANDS   16
#define BANDH    65                 // 16*65 = 1040 >= 1025
#define WAVES_PER_BLOCK 4
#define NTHREADS 256
#define NWAVES  (NSTRIPS * NBANDS * NIMG)    // 4352
#define NBLOCKS (NWAVES / WAVES_PER_BLOCK)   // 1088 (exact)

#define GR_W 68                     // LDS ring row stride (dwords)
#define LDS_PER_WAVE_DW (2 * 4 * GR_W)       // g ring (4 rows) + b ring (4 rows)

// Map bp (double-reflect-padded) row/col index k in [0,1026] to source image index.
__device__ __forceinline__ int refl_idx(int k) {
    if (k >= 2) return (k <= 1025) ? (k - 2) : 1022;
    return k;
}
__device__ __forceinline__ int clamp0(int k, int hi) {
    return k < 0 ? 0 : (k > hi ? hi : k);
}

// Exact reference binning (double atan2 -> f32 chain). Bit-matched np in r1.
// COLD path: only hit inside a ~1e-4-wide guard band around the bin edges.
__device__ int classify_slow(float gx, float gy) {
    float t = (float)atan2((double)gx, (double)gy);
    float deg = __fmul_rn(t, (float)(180.0 / M_PI));
    float th = __fadd_rn(deg, 90.0f);
    th = fmodf(th, 180.0f);
    if (th < 0.0f) th += 180.0f;
    if (th < 22.5f || th >= 157.5f) return 0;
    if (th < 67.5f) return 1;
    if (th < 112.5f) return 2;
    return 3;
}

// Fast binning: sign + ratio comparisons with guard band (bit-matched np in r2/r3).
__device__ __forceinline__ int classify(float gx, float gy) {
    float ax = fabsf(gx), ay = fabsf(gy);
    const float T22_LO = 0.414172141e0f;
    const float T22_HI = 0.414254984e0f;
    const float T67_LO = 2.413972141e0f;
    const float T67_HI = 2.414454984e0f;

    if (ax <= ay * T22_LO) return 2;                  // (0,0) lands here: bin 2
    if (ax >= ay * T67_HI) return 0;
    if (ax >= ay * T22_HI && ax <= ay * T67_LO) {
        unsigned s = (__float_as_uint(gx) ^ __float_as_uint(gy)) >> 31;
        return s ? 1 : 3;
    }
    return classify_slow(gx, gy);
}

__device__ __forceinline__ float mag(float gx, float gy) {
    return __fsqrt_rn(__fadd_rn(__fmul_rn(gx, gx), __fmul_rn(gy, gy)));
}

// launch_bounds(256,5): VGPR cap ~102 (no hot-path spill risk); grid only needs
// 17 waves/CU resident (4352 waves total) which this guarantees.
__global__ __launch_bounds__(NTHREADS, 5) void canny_kernel(const float* __restrict__ images,
                                                            float* __restrict__ out) {
    __shared__ float lds[WAVES_PER_BLOCK * LDS_PER_WAVE_DW];   // 8704 B

    const int tid = threadIdx.x;
    const int w   = tid >> 6;
    const int L   = tid & 63;

    const int gw    = blockIdx.x * WAVES_PER_BLOCK + w;
    const int img_i = gw / (NSTRIPS * NBANDS);
    const int rem   = gw - img_i * (NSTRIPS * NBANDS);
    const int band  = rem / NSTRIPS;
    const int strip = rem - band * NSTRIPS;

    const float* img = images + (size_t)img_i * IMG_H * IMG_W;

    const int col0 = strip * STRIPW;
    const int c    = col0 - 1 + L;          // out col this lane produces g for
    // Per-lane img columns for bp cols c, c+1, c+2 — ALL column reflection
    // (left edge, right edge) is folded into these three constants.
    const int mc0 = refl_idx(clamp0(c,     1026));
    const int mc1 = refl_idx(clamp0(c + 1, 1026));
    const int mc2 = refl_idx(clamp0(c + 2, 1026));

    const int ys = band * BANDH;
    const int ye = min(ys + BANDH, OUT_H);  // out rows [ys, ye)
    const int gs = max(ys - 1, 0);          // first g row needed (NMS halo)
    const int ge = min(ye, 1024);           // last g row computable
    const int tmax = ye - gs;               // last iteration (NMS y = ye-1)

    float*    gring = lds + w * LDS_PER_WAVE_DW;          // 4 rows x GR_W
    unsigned* bring = (unsigned*)(gring + 4 * GR_W);      // 4 rows x GR_W

    const bool laneValid = (c >= 0 && c <= 1024);
    const bool storeLane = (L >= 1 && L <= 62 && c <= 1024);

    // img row pointer for bp row k (row reflection folded here)
    const float* __restrict__ imgr = img;
    #define ROWPTR(k) (imgr + (size_t)refl_idx((k) > 1026 ? 1026 : (k)) * IMG_W)

    // ---- prologue: warm up 2 rows + 4-deep prefetch ----
    const float* rp;
    rp = ROWPTR(gs);     float T0a = rp[mc0], T0b = rp[mc1], T0c = rp[mc2];
    rp = ROWPTR(gs + 1); float T1a = rp[mc0], T1b = rp[mc1], T1c = rp[mc2];
    float Pa[4], Pb[4], Pc[4];
    #pragma unroll
    for (int j = 0; j < 4; ++j) {
        rp = ROWPTR(gs + 2 + j);
        Pa[j] = rp[mc0]; Pb[j] = rp[mc1]; Pc[j] = rp[mc2];
    }
    float prevG = 0.0f; unsigned prevB = 255u;

    for (int t0 = 0; t0 <= tmax; t0 += 4) {
        #pragma unroll
        for (int j = 0; j < 4; ++j) {
            const int t = t0 + j;
            if (t > tmax) break;
            const int i = gs + t;           // g row produced this iteration
            float g = -1.0f; unsigned b = 255u;

            if (i <= ge) {
                // consume P[j] = bp row i+2 (loaded 4 iterations ago)
                float v20 = Pa[j], v21 = Pb[j], v22 = Pc[j];
                float v00 = T0a,  v01 = T0b,  v02 = T0c;
                float v10 = T1a,              v12 = T1c;

                float s = -v00;
                s = __fadd_rn(s, v02);
                s = __fadd_rn(s, -2.0f * v10);
                s = __fadd_rn(s, 2.0f * v12);
                s = __fadd_rn(s, -v20);
                float gx = __fadd_rn(s, v22);

                s = -v00;
                s = __fadd_rn(s, -2.0f * v01);
                s = __fadd_rn(s, -v02);
                s = __fadd_rn(s, v20);
                s = __fadd_rn(s, 2.0f * v21);
                float gy = __fadd_rn(s, v22);

                if (laneValid) {
                    g = mag(gx, gy);
                    b = (unsigned)classify(gx, gy);
                }

                int slot = (i & 3) * GR_W + (L + 1);
                gring[slot] = g;
                bring[slot] = b;

                // rotate row triples (completed values only — no pending-load movs)
                T0a = T1a; T0b = T1b; T0c = T1c;
                T1a = v20; T1b = v21; T1c = v22;
            }

            // ---- NMS for out row y = i-1 (wave-uniform guard) ----
            const int y = i - 1;
            if (y >= ys && y < ye) {
                float    gc = prevG;
                unsigned bc = prevB;
                int dy = (bc == 0u) ? 0 : 1;
                int dx = (bc == 0u) ? 1 : (bc == 1u) ? -1 : (bc == 2u) ? 0 : 1;
                int p1 = ((unsigned)(y + dy) & 3u) * GR_W + (L + 1 + dx);
                int p2 = ((unsigned)(y - dy) & 3u) * GR_W + (L + 1 - dx);
                float    n1g = gring[p1]; unsigned n1b = bring[p1];
                float    n2g = gring[p2]; unsigned n2b = bring[p2];
                bool v1 = (y + dy) <= 1024;   // row-halo validity (band/image edge)
                bool v2 = (y - dy) >= 0;
                float nmax = 0.0f;
                if (v1 && n1b == bc && n1g > nmax) nmax = n1g;
                if (v2 && n2b == bc && n2g > nmax) nmax = n2g;
                float e = (gc >= nmax) ? gc : 0.0f;

                if (storeLane) {
                    size_t o = (size_t)(img_i * OUT_H + y) * OUT_W + c;
                    out[o]                         = (e >= 50.0f) ? 255.5f : 0.0f;
                    out[(size_t)TOTAL + o]         = (e >= 50.0f && e < 100.0f) ? 255.0f : 0.0f;
                    out[(size_t)(2 * TOTAL) + o]   = (e >= 100.0f) ? 255.0f : 0.0f;
                }
            }

            if (i <= ge) { prevG = g; prevB = b; }

            // ---- prefetch bp row i+6 into P[j] (consumed at t+4) ----
            if (i + 6 <= ge + 2) {
                rp = ROWPTR(i + 6);
                Pa[j] = rp[mc0]; Pb[j] = rp[mc1]; Pc[j] = rp[mc2];
            }
        }
    }
    #undef ROWPTR
}

extern "C" void kernel_launch(void* const* d_in, const int* in_sizes, int n_in,
                              void* d_out, int out_size, void* d_ws, size_t ws_size,
                              hipStream_t stream) {
    const float* images = (const float*)d_in[0];
    float* outp = (float*)d_out;
    dim3 grid(NBLOCKS, 1, 1);
    canny_kernel<<<grid, NTHREADS, 0, stream>>>(images, outp);
}